// Round 4
// baseline (921.890 us; speedup 1.0000x reference)
//
#include <hip/hip_runtime.h>
#include <hip/hip_bf16.h>
#include <hip/hip_fp16.h>

#define N_NODES 100000
#define N_EDGES 1600000
#define NF 64
#define EF 32

// Sort-free design: edges processed in original order; per-node aggregation
// via coalesced f32 atomics into L2/L3-resident accumulators.
//   acc_ms[n][64] += ex * m_src[src]      (64-lane contiguous atomic)
//   acc_ef[n][32] += ex * ef              (32-lane contiguous atomic)
//   sum_ex[n]     += ex                   (1-lane atomic)
// k4: out = (acc_ms + Wme@acc_ef)/sum_ex + m_dst + b, relu.

__device__ __forceinline__ unsigned pkh2(float a, float b) {
  __half2 h = __floats2half2_rn(a, b);
  return *reinterpret_cast<unsigned*>(&h);
}

// ---------------- K0: tiny prep — v = W_w^T a (160), c = W_b . a, and
// transposed copies of W_msg sub-blocks.
__global__ __launch_bounds__(256) void k0_prep(
    const float* __restrict__ Ww, const float* __restrict__ Wb,
    const float* __restrict__ a, const float* __restrict__ Wmsg,
    float* __restrict__ v, float* __restrict__ W1T, float* __restrict__ W2T,
    float* __restrict__ WmeT) {
  int t = threadIdx.x;
  for (int j = t; j < 160; j += 256) {
    float s = 0.f;
    for (int k = 0; k < 128; ++k) s = fmaf(a[k], Ww[k * 160 + j], s);
    v[j] = s;
  }
  if (t == 0) {
    float s = 0.f;
    for (int k = 0; k < 128; ++k) s = fmaf(a[k], Wb[k], s);
    v[160] = s;  // c
  }
  for (int idx = t; idx < 64 * 64; idx += 256) {
    int j = idx >> 6, i = idx & 63;
    W1T[idx] = Wmsg[i * 160 + j];        // src block, transposed [j][i]
    W2T[idx] = Wmsg[i * 160 + 64 + j];   // dst block
  }
  for (int idx = t; idx < 32 * 64; idx += 256) {
    int j = idx >> 6, i = idx & 63;
    WmeT[idx] = Wmsg[i * 160 + 128 + j]; // edge block
  }
}

// ---------------- K1: per-node precompute — s1, s2 scalars and
// m_src (fp16) = W1 @ nf, m_dst (f32) = W2 @ nf.
__global__ __launch_bounds__(256) void k1_node(
    const float* __restrict__ nf_g, const float* __restrict__ v,
    const float* __restrict__ W1T, const float* __restrict__ W2T,
    float* __restrict__ s1, float* __restrict__ s2,
    __half* __restrict__ m_src_h, float* __restrict__ m_dst) {
  int n = blockIdx.x * 256 + threadIdx.x;
  if (n >= N_NODES) return;
  const float4* nf4 = (const float4*)(nf_g + (size_t)n * NF);
  float acc[64];
#pragma unroll
  for (int i = 0; i < 64; ++i) acc[i] = 0.f;
  float s1a = 0.f, s2a = 0.f;
  for (int j4 = 0; j4 < 16; ++j4) {
    float4 q = nf4[j4];
    float xs[4] = {q.x, q.y, q.z, q.w};
#pragma unroll
    for (int u = 0; u < 4; ++u) {
      int j = j4 * 4 + u;
      float x = xs[u];
      s1a = fmaf(v[j], x, s1a);
      s2a = fmaf(v[64 + j], x, s2a);
      const float* w = W1T + j * 64;
#pragma unroll
      for (int i = 0; i < 64; ++i) acc[i] = fmaf(w[i], x, acc[i]);
    }
  }
  s1[n] = s1a;
  s2[n] = s2a;
  uint4* ms4 = (uint4*)(m_src_h + (size_t)n * NF);
#pragma unroll
  for (int b = 0; b < 8; ++b)
    ms4[b] = make_uint4(pkh2(acc[b * 8 + 0], acc[b * 8 + 1]),
                        pkh2(acc[b * 8 + 2], acc[b * 8 + 3]),
                        pkh2(acc[b * 8 + 4], acc[b * 8 + 5]),
                        pkh2(acc[b * 8 + 6], acc[b * 8 + 7]));
#pragma unroll
  for (int i = 0; i < 64; ++i) acc[i] = 0.f;
  for (int j4 = 0; j4 < 16; ++j4) {
    float4 q = nf4[j4];
    float xs[4] = {q.x, q.y, q.z, q.w};
#pragma unroll
    for (int u = 0; u < 4; ++u) {
      int j = j4 * 4 + u;
      float x = xs[u];
      const float* w = W2T + j * 64;
#pragma unroll
      for (int i = 0; i < 64; ++i) acc[i] = fmaf(w[i], x, acc[i]);
    }
  }
  float* md = m_dst + (size_t)n * NF;
#pragma unroll
  for (int i = 0; i < 64; ++i) md[i] = acc[i];
}

// ---------------- kE_fused: one wave per 2 edges (grid-stride). Half-wave
// computes each edge's ex from f32 ef; then coalesced vector atomics.
__global__ __launch_bounds__(256) void kE_fused(
    const int2* __restrict__ src2, const int2* __restrict__ dst2,
    const float* __restrict__ e_feat, const float* __restrict__ s1,
    const float* __restrict__ s2, const float* __restrict__ v,
    const __half* __restrict__ m_src_h, float* __restrict__ sum_ex,
    float* __restrict__ acc_ef, float* __restrict__ acc_ms) {
  int lane = threadIdx.x & 63;
  int wv = (blockIdx.x * 256 + threadIdx.x) >> 6;  // global wave id
  int nw = (gridDim.x * 256) >> 6;
  int half = lane >> 5;
  int hl = lane & 31;
  float vv = v[128 + hl];  // attention weight for this ef column
  float cb = v[160];
  for (int p = wv; p < N_EDGES / 2; p += nw) {
    int2 sp = src2[p];
    int2 dp = dst2[p];
    int sn = half ? sp.y : sp.x;
    int dn = half ? dp.y : dp.x;
    // ef for both edges: lane reads e_feat[2p*32 + lane] (256B coalesced)
    float ef = e_feat[(size_t)p * 64 + lane];
    float t = ef * vv;
    t += __shfl_xor(t, 1);
    t += __shfl_xor(t, 2);
    t += __shfl_xor(t, 4);
    t += __shfl_xor(t, 8);
    t += __shfl_xor(t, 16);  // reduce within the 32-lane half
    float lg = s1[sn] + s2[dn] + t + cb;
    float l = lg > 0.f ? lg : 0.01f * lg;  // leaky_relu(0.01)
    float ex = __expf(l);
    // m_src gathers for both edges (coalesced 128B each), issued early
    float ms0 = __half2float(m_src_h[(size_t)sp.x * NF + lane]);
    float ms1 = __half2float(m_src_h[(size_t)sp.y * NF + lane]);
    // acc_ef: one atomic instruction covering both edges (2x128B segments)
    atomicAdd(&acc_ef[(size_t)dn * EF + hl], ex * ef);
    if (hl == 0) atomicAdd(&sum_ex[dn], ex);
    float ex0 = __shfl(ex, 0);
    float ex1 = __shfl(ex, 32);
    atomicAdd(&acc_ms[(size_t)dp.x * NF + lane], ex0 * ms0);
    atomicAdd(&acc_ms[(size_t)dp.y * NF + lane], ex1 * ms1);
  }
}

// ---------------- k4: finalize per node (wave per node, lane = feature).
__global__ __launch_bounds__(256) void k4_final(
    const float* __restrict__ sum_ex, const float* __restrict__ acc_ef,
    const float* __restrict__ acc_ms, const float* __restrict__ m_dst,
    const float* __restrict__ WmeT, const float* __restrict__ Wmsg_b,
    float* __restrict__ out) {
  int lane = threadIdx.x & 63;
  int wid = threadIdx.x >> 6;
  int n = blockIdx.x * 4 + wid;
  if (n >= N_NODES) return;
  float se = sum_ex[n];
  float af = acc_ef[(size_t)n * EF + (lane & 31)];
  float am = acc_ms[(size_t)n * NF + lane];
  float mm = 0.f;
#pragma unroll
  for (int j = 0; j < 32; ++j) {
    float aj = __shfl(af, j);
    mm = fmaf(WmeT[j * 64 + lane], aj, mm);
  }
  float o = 0.f;
  if (se > 0.f) {
    o = (am + mm) / se + m_dst[(size_t)n * NF + lane] + Wmsg_b[lane];
    o = fmaxf(o, 0.f);
  }
  out[(size_t)n * NF + lane] = o;
}

extern "C" void kernel_launch(void* const* d_in, const int* in_sizes, int n_in,
                              void* d_out, int out_size, void* d_ws,
                              size_t ws_size, hipStream_t stream) {
  const float* n_feat = (const float*)d_in[0];
  const float* e_feat = (const float*)d_in[1];
  const int* src = (const int*)d_in[2];
  const int* dst = (const int*)d_in[3];
  const float* Wmsg_w = (const float*)d_in[4];
  const float* Wmsg_b = (const float*)d_in[5];
  const float* W_w = (const float*)d_in[6];
  const float* W_b = (const float*)d_in[7];
  const float* a = (const float*)d_in[8];
  float* out = (float*)d_out;

  char* ws = (char*)d_ws;
  size_t off = 0;
  auto alloc = [&](size_t bytes) -> char* {
    char* p = ws + off;
    off = (off + bytes + 255) & ~(size_t)255;
    return p;
  };
  float* v = (float*)alloc(161 * 4);
  float* W1T = (float*)alloc(64 * 64 * 4);
  float* W2T = (float*)alloc(64 * 64 * 4);
  float* WmeT = (float*)alloc(32 * 64 * 4);
  float* s1 = (float*)alloc(N_NODES * 4);
  float* s2 = (float*)alloc(N_NODES * 4);
  __half* m_src_h = (__half*)alloc((size_t)N_NODES * NF * 2);
  float* m_dst = (float*)alloc((size_t)N_NODES * NF * 4);
  // zeroed accumulator region (contiguous -> single memset)
  char* zstart = ws + off;
  float* sum_ex = (float*)alloc(N_NODES * 4);
  float* acc_ef = (float*)alloc((size_t)N_NODES * EF * 4);
  float* acc_ms = (float*)alloc((size_t)N_NODES * NF * 4);
  size_t zbytes = (size_t)((ws + off) - zstart);
  if (off > ws_size) return;  // workspace too small — fail loudly in check

  hipMemsetAsync(zstart, 0, zbytes, stream);
  k0_prep<<<1, 256, 0, stream>>>(W_w, W_b, a, Wmsg_w, v, W1T, W2T, WmeT);
  k1_node<<<(N_NODES + 255) / 256, 256, 0, stream>>>(n_feat, v, W1T, W2T, s1,
                                                     s2, m_src_h, m_dst);
  kE_fused<<<1024, 256, 0, stream>>>((const int2*)src, (const int2*)dst,
                                     e_feat, s1, s2, v, m_src_h, sum_ex,
                                     acc_ef, acc_ms);
  k4_final<<<(N_NODES + 3) / 4, 256, 0, stream>>>(sum_ex, acc_ef, acc_ms,
                                                  m_dst, WmeT, Wmsg_b, out);
}

// Round 5
// 602.175 us; speedup vs baseline: 1.5309x; 1.5309x over previous
//
#include <hip/hip_runtime.h>
#include <hip/hip_bf16.h>
#include <hip/hip_fp16.h>

#define N_NODES 100000
#define N_EDGES 1600000
#define NF 64
#define EF 32

#define SCAN_B 512
#define SCAN_NB ((N_NODES + SCAN_B - 1) / SCAN_B)  // 196
#define CNT_NB ((N_EDGES + 255) / 256)             // 6250
#define K1_NB ((N_NODES + 511) / 512)              // 196

// ef_s: per-edge sorted record, 64B = 32 x fp16 ef values with 33 bits
// stolen:
//   src bits 0..15  -> LSB (bit 0) of words 0..15
//   src bit 16      -> bit 16 of word 0
//   l fp16 bits 0..14 -> bit 16 of words 1..15   (l = leaky(logit), f16)
//   l fp16 bit 15 (sign) -> bit 1 of word 0
// k3 reconstructs all four (src, l) of a 4-edge group from 3 ballots and
// computes ex = exp(l) per lane — no gathers/reduces on the ex path.

__device__ __forceinline__ unsigned pkh2(float a, float b) {
  __half2 h = __floats2half2_rn(a, b);
  return *reinterpret_cast<unsigned*>(&h);
}

// ---------------- kA: fused degree-count (blocks 0..CNT_NB-1) and weight
// prep (last block): v = W_w^T a, c = W_b . a, W_msg transposes.
__global__ __launch_bounds__(256) void kA_count_prep(
    const int* __restrict__ dst, int* __restrict__ cnt,
    const float* __restrict__ Ww, const float* __restrict__ Wb,
    const float* __restrict__ a, const float* __restrict__ Wmsg,
    float* __restrict__ v, float* __restrict__ W1T, float* __restrict__ W2T,
    float* __restrict__ WmeT) {
  int b = blockIdx.x;
  int t = threadIdx.x;
  if (b < CNT_NB) {
    int e = b * 256 + t;
    if (e < N_EDGES) atomicAdd(&cnt[dst[e]], 1);
    return;
  }
  // ---- prep block ----
  for (int j = t; j < 160; j += 256) {
    float s = 0.f;
    for (int k = 0; k < 128; ++k) s = fmaf(a[k], Ww[k * 160 + j], s);
    v[j] = s;
  }
  if (t == 0) {
    float s = 0.f;
    for (int k = 0; k < 128; ++k) s = fmaf(a[k], Wb[k], s);
    v[160] = s;  // c
  }
  for (int idx = t; idx < 64 * 64; idx += 256) {
    int j = idx >> 6, i = idx & 63;
    W1T[idx] = Wmsg[i * 160 + j];        // src block, transposed [j][i]
    W2T[idx] = Wmsg[i * 160 + 64 + j];   // dst block
  }
  for (int idx = t; idx < 32 * 64; idx += 256) {
    int j = idx >> 6, i = idx & 63;
    WmeT[idx] = Wmsg[i * 160 + 128 + j]; // edge block
  }
}

// ---------------- kB: fused scan-stage-1 (blocks 0..SCAN_NB-1) and per-node
// precompute (remaining blocks): s1,s2 scalars, m_src fp16, m_dst f32.
__global__ __launch_bounds__(512) void kB_scan1_node(
    const int* __restrict__ cnt, int* __restrict__ bsum,
    const float* __restrict__ nf_g, const float* __restrict__ v,
    const float* __restrict__ W1T, const float* __restrict__ W2T,
    float* __restrict__ s1, float* __restrict__ s2,
    __half* __restrict__ m_src_h, float* __restrict__ m_dst) {
  __shared__ int sh[SCAN_B];
  int t = threadIdx.x;
  if (blockIdx.x < SCAN_NB) {
    int i = blockIdx.x * SCAN_B + t;
    sh[t] = (i < N_NODES) ? cnt[i] : 0;
    __syncthreads();
    for (int d = SCAN_B / 2; d > 0; d >>= 1) {
      if (t < d) sh[t] += sh[t + d];
      __syncthreads();
    }
    if (t == 0) bsum[blockIdx.x] = sh[0];
    return;
  }
  // ---- per-node part ----
  int n = (blockIdx.x - SCAN_NB) * 512 + t;
  if (n >= N_NODES) return;
  const float4* nf4 = (const float4*)(nf_g + (size_t)n * NF);
  float acc[64];
#pragma unroll
  for (int i = 0; i < 64; ++i) acc[i] = 0.f;
  float s1a = 0.f, s2a = 0.f;
  for (int j4 = 0; j4 < 16; ++j4) {
    float4 q = nf4[j4];
    float xs[4] = {q.x, q.y, q.z, q.w};
#pragma unroll
    for (int u = 0; u < 4; ++u) {
      int j = j4 * 4 + u;
      float x = xs[u];
      s1a = fmaf(v[j], x, s1a);
      s2a = fmaf(v[64 + j], x, s2a);
      const float* w = W1T + j * 64;
#pragma unroll
      for (int i = 0; i < 64; ++i) acc[i] = fmaf(w[i], x, acc[i]);
    }
  }
  s1[n] = s1a;
  s2[n] = s2a;
  uint4* ms4 = (uint4*)(m_src_h + (size_t)n * NF);
#pragma unroll
  for (int b = 0; b < 8; ++b)
    ms4[b] = make_uint4(pkh2(acc[b * 8 + 0], acc[b * 8 + 1]),
                        pkh2(acc[b * 8 + 2], acc[b * 8 + 3]),
                        pkh2(acc[b * 8 + 4], acc[b * 8 + 5]),
                        pkh2(acc[b * 8 + 6], acc[b * 8 + 7]));
#pragma unroll
  for (int i = 0; i < 64; ++i) acc[i] = 0.f;
  for (int j4 = 0; j4 < 16; ++j4) {
    float4 q = nf4[j4];
    float xs[4] = {q.x, q.y, q.z, q.w};
#pragma unroll
    for (int u = 0; u < 4; ++u) {
      int j = j4 * 4 + u;
      float x = xs[u];
      const float* w = W2T + j * 64;
#pragma unroll
      for (int i = 0; i < 64; ++i) acc[i] = fmaf(w[i], x, acc[i]);
    }
  }
  float* md = m_dst + (size_t)n * NF;
#pragma unroll
  for (int i = 0; i < 64; ++i) md[i] = acc[i];
}

// ---------------- kS23: merged scan stages 2+3. Each block redundantly
// prefix-sums the 196 bsum entries in LDS, then scans its cnt chunk.
__global__ __launch_bounds__(SCAN_B) void kS23(const int* __restrict__ cnt,
                                               const int* __restrict__ bsum,
                                               int* __restrict__ row_ptr,
                                               int* __restrict__ cursor) {
  __shared__ int sb[256];
  __shared__ int sh[SCAN_B];
  int t = threadIdx.x;
  if (t < 256) sb[t] = (t < SCAN_NB) ? bsum[t] : 0;
  __syncthreads();
  for (int d = 1; d < 256; d <<= 1) {
    int val = 0;
    if (t < 256 && t >= d) val = sb[t - d];
    __syncthreads();
    if (t < 256) sb[t] += val;
    __syncthreads();
  }
  int boff = (blockIdx.x == 0) ? 0 : sb[blockIdx.x - 1];
  int i = blockIdx.x * SCAN_B + t;
  int val = (i < N_NODES) ? cnt[i] : 0;
  sh[t] = val;
  __syncthreads();
  for (int d = 1; d < SCAN_B; d <<= 1) {
    int u = (t >= d) ? sh[t - d] : 0;
    __syncthreads();
    sh[t] += u;
    __syncthreads();
  }
  if (i < N_NODES) {
    int excl = boff + sh[t] - val;
    row_ptr[i] = excl;
    cursor[i] = excl;
  }
  if (blockIdx.x == 0 && t == 0) row_ptr[N_NODES] = sb[SCAN_NB - 1];
}

// ---------------- kE: compute l = leaky(logit) from full-f32 ef, pack the
// fp16 record with src(17b)+l(16b) bit-stolen, ONE 64B scattered write.
__global__ __launch_bounds__(256) void kE_scatter(
    const int* __restrict__ src, const int* __restrict__ dst,
    const float* __restrict__ e_feat, const float* __restrict__ s1,
    const float* __restrict__ s2, const float* __restrict__ v,
    int* __restrict__ cursor, uint4* __restrict__ ef_s4) {
  int e = blockIdx.x * 256 + threadIdx.x;
  if (e >= N_EDGES) return;
  unsigned sn = (unsigned)src[e];
  int dn = dst[e];
  const float4* efr = (const float4*)(e_feat + (size_t)e * EF);
  float4 q[8];
#pragma unroll
  for (int i = 0; i < 8; ++i) q[i] = efr[i];
  float t = 0.f;
#pragma unroll
  for (int i = 0; i < 8; ++i) {
    t = fmaf(q[i].x, v[128 + i * 4 + 0], t);
    t = fmaf(q[i].y, v[128 + i * 4 + 1], t);
    t = fmaf(q[i].z, v[128 + i * 4 + 2], t);
    t = fmaf(q[i].w, v[128 + i * 4 + 3], t);
  }
  float lg = s1[sn] + s2[dn] + t + v[160];
  float l = lg > 0.f ? lg : 0.01f * lg;  // leaky_relu(0.01)
  unsigned lh = (unsigned)__half_as_ushort(__float2half_rn(l));
  int p = atomicAdd(&cursor[dn], 1);
  unsigned u[16];
#pragma unroll
  for (int i = 0; i < 8; ++i) {
    u[2 * i] = pkh2(q[i].x, q[i].y);
    u[2 * i + 1] = pkh2(q[i].z, q[i].w);
  }
#pragma unroll
  for (int j = 0; j < 16; ++j)
    u[j] = (u[j] & ~1u) | ((sn >> j) & 1u);
#pragma unroll
  for (int j = 1; j < 16; ++j)
    u[j] = (u[j] & ~0x10000u) | (((lh >> (j - 1)) & 1u) << 16);
  u[0] = (u[0] & ~0x10002u) | (((sn >> 16) & 1u) << 16) |
         (((lh >> 15) & 1u) << 1);
  uint4* o = ef_s4 + (size_t)p * 4;
  o[0] = make_uint4(u[0], u[1], u[2], u[3]);
  o[1] = make_uint4(u[4], u[5], u[6], u[7]);
  o[2] = make_uint4(u[8], u[9], u[10], u[11]);
  o[3] = make_uint4(u[12], u[13], u[14], u[15]);
}

// ---------------- K3: one wave per dst node. Sequential record stream;
// 3 ballots give every lane all 4 (src, l) of the group — no s1 gather,
// no shuffle-reduce. m_src gathers pipelined one group ahead.
__global__ __launch_bounds__(256) void k3_agg(
    const int* __restrict__ row_ptr, const unsigned* __restrict__ efu,
    const __half* __restrict__ m_src_h, const float* __restrict__ m_dst,
    const float* __restrict__ WmeT, const float* __restrict__ Wmsg_b,
    float* __restrict__ out) {
  int lane = threadIdx.x & 63;
  int wid = threadIdx.x >> 6;
  int n = blockIdx.x * 4 + wid;
  if (n >= N_NODES) return;
  int start = row_ptr[n];
  int end = row_ptr[n + 1];
  int g = lane >> 4;   // edge-of-4 this lane's record word belongs to
  int w = lane & 15;   // word index within the record
  float sum_ex = 0.f, acc_ms = 0.f;
  float aefx = 0.f, aefy = 0.f;
  if (start < end) {
    unsigned ucur = efu[(size_t)min(start + g, N_EDGES - 1) * 16 + w];
    unsigned unxt = efu[(size_t)min(start + 4 + g, N_EDGES - 1) * 16 + w];
    unsigned long long b0 = __ballot((int)(ucur & 1u));
    unsigned long long b1 = __ballot((int)(ucur & 0x10000u));
    unsigned long long b2 = __ballot((int)(ucur & 2u));
    float lA[4];
    __half hA[4];
#pragma unroll
    for (int gg = 0; gg < 4; ++gg) {
      int sh16 = gg << 4;
      int s = (int)((b0 >> sh16) & 0xFFFFull) |
              ((int)((b1 >> sh16) & 1ull) << 16);
      s = min(s, N_NODES - 1);
      unsigned lb = (unsigned)((b1 >> (sh16 + 1)) & 0x7FFFull) |
                    ((unsigned)((b2 >> sh16) & 1ull) << 15);
      lA[gg] = __half2float(__ushort_as_half((unsigned short)lb));
      hA[gg] = m_src_h[(size_t)s * NF + lane];
    }
    for (int k = start; k < end; k += 4) {
      unsigned ufar = efu[(size_t)min(k + 8 + g, N_EDGES - 1) * 16 + w];
      // decode + issue gathers for group k+4 (consumed next iteration)
      unsigned long long c0 = __ballot((int)(unxt & 1u));
      unsigned long long c1 = __ballot((int)(unxt & 0x10000u));
      unsigned long long c2m = __ballot((int)(unxt & 2u));
      float lB[4];
      __half hB[4];
#pragma unroll
      for (int gg = 0; gg < 4; ++gg) {
        int sh16 = gg << 4;
        int s = (int)((c0 >> sh16) & 0xFFFFull) |
                ((int)((c1 >> sh16) & 1ull) << 16);
        s = min(s, N_NODES - 1);
        unsigned lb = (unsigned)((c1 >> (sh16 + 1)) & 0x7FFFull) |
                      ((unsigned)((c2m >> sh16) & 1ull) << 15);
        lB[gg] = __half2float(__ushort_as_half((unsigned short)lb));
        hB[gg] = m_src_h[(size_t)s * NF + lane];
      }
      // consume current group: ex = exp(l), pad slots masked to 0
      float e0 = (k + 0 < end) ? __expf(lA[0]) : 0.f;
      float e1 = (k + 1 < end) ? __expf(lA[1]) : 0.f;
      float e2 = (k + 2 < end) ? __expf(lA[2]) : 0.f;
      float e3 = (k + 3 < end) ? __expf(lA[3]) : 0.f;
      __half2 h2 = *reinterpret_cast<__half2*>(&ucur);
      float2 ef2 = __half22float2(h2);
      float eg = (g == 0) ? e0 : (g == 1) ? e1 : (g == 2) ? e2 : e3;
      aefx = fmaf(eg, ef2.x, aefx);
      aefy = fmaf(eg, ef2.y, aefy);
      sum_ex += (e0 + e1) + (e2 + e3);
      acc_ms = fmaf(e0, __half2float(hA[0]), acc_ms);
      acc_ms = fmaf(e1, __half2float(hA[1]), acc_ms);
      acc_ms = fmaf(e2, __half2float(hA[2]), acc_ms);
      acc_ms = fmaf(e3, __half2float(hA[3]), acc_ms);
      // rotate pipeline
      ucur = unxt;
      unxt = ufar;
#pragma unroll
      for (int gg = 0; gg < 4; ++gg) {
        lA[gg] = lB[gg];
        hA[gg] = hB[gg];
      }
    }
  }
  // reduce ef accumulators across the 4 lane-groups (same word at
  // lanes w, w+16, w+32, w+48)
  aefx += __shfl_xor(aefx, 16);
  aefx += __shfl_xor(aefx, 32);
  aefy += __shfl_xor(aefy, 16);
  aefy += __shfl_xor(aefy, 32);
  // mm[lane] = sum_j Wme[lane][j] * aef[j]; lane jp holds cols {2jp,2jp+1}
  float mm = 0.f;
#pragma unroll
  for (int jp = 0; jp < 16; ++jp) {
    float ea = __shfl(aefx, jp);
    float eb = __shfl(aefy, jp);
    mm = fmaf(WmeT[(2 * jp) * 64 + lane], ea, mm);
    mm = fmaf(WmeT[(2 * jp + 1) * 64 + lane], eb, mm);
  }
  float o = 0.f;
  if (sum_ex > 0.f) {
    o = (acc_ms + mm) / sum_ex + m_dst[(size_t)n * NF + lane] + Wmsg_b[lane];
    o = fmaxf(o, 0.f);
  }
  out[(size_t)n * NF + lane] = o;
}

extern "C" void kernel_launch(void* const* d_in, const int* in_sizes, int n_in,
                              void* d_out, int out_size, void* d_ws,
                              size_t ws_size, hipStream_t stream) {
  const float* n_feat = (const float*)d_in[0];
  const float* e_feat = (const float*)d_in[1];
  const int* src = (const int*)d_in[2];
  const int* dst = (const int*)d_in[3];
  const float* Wmsg_w = (const float*)d_in[4];
  const float* Wmsg_b = (const float*)d_in[5];
  const float* W_w = (const float*)d_in[6];
  const float* W_b = (const float*)d_in[7];
  const float* a = (const float*)d_in[8];
  float* out = (float*)d_out;

  char* ws = (char*)d_ws;
  size_t off = 0;
  auto alloc = [&](size_t bytes) -> char* {
    char* p = ws + off;
    off = (off + bytes + 255) & ~(size_t)255;
    return p;
  };
  float* v = (float*)alloc(161 * 4);
  float* W1T = (float*)alloc(64 * 64 * 4);
  float* W2T = (float*)alloc(64 * 64 * 4);
  float* WmeT = (float*)alloc(32 * 64 * 4);
  float* s1 = (float*)alloc(N_NODES * 4);
  float* s2 = (float*)alloc(N_NODES * 4);
  __half* m_src_h = (__half*)alloc((size_t)N_NODES * NF * 2);
  float* m_dst = (float*)alloc((size_t)N_NODES * NF * 4);
  int* cnt = (int*)alloc(N_NODES * 4);
  int* row_ptr = (int*)alloc((N_NODES + 1) * 4);
  int* cursor = (int*)alloc(N_NODES * 4);
  int* bsum = (int*)alloc(SCAN_NB * 4);
  __half* ef_s = (__half*)alloc(((size_t)N_EDGES + 8) * EF * 2);
  if (off > ws_size) return;  // workspace too small — fail loudly in check

  hipMemsetAsync(cnt, 0, N_NODES * 4, stream);
  kA_count_prep<<<CNT_NB + 1, 256, 0, stream>>>(dst, cnt, W_w, W_b, a,
                                                Wmsg_w, v, W1T, W2T, WmeT);
  kB_scan1_node<<<SCAN_NB + K1_NB, 512, 0, stream>>>(
      cnt, bsum, n_feat, v, W1T, W2T, s1, s2, m_src_h, m_dst);
  kS23<<<SCAN_NB, SCAN_B, 0, stream>>>(cnt, bsum, row_ptr, cursor);
  kE_scatter<<<(N_EDGES + 255) / 256, 256, 0, stream>>>(
      src, dst, e_feat, s1, s2, v, cursor, (uint4*)ef_s);
  k3_agg<<<(N_NODES + 3) / 4, 256, 0, stream>>>(
      row_ptr, (const unsigned*)ef_s, m_src_h, m_dst, WmeT, Wmsg_b, out);
}